// Round 2
// baseline (641.089 us; speedup 1.0000x reference)
//
#include <hip/hip_runtime.h>
#include <stdint.h>

// Problem constants (exact multiples of tile sizes — no bounds checks)
#define M_DIM 4096      // 2*2048 rows of x
#define K_DIM 4096      // in_features
#define N_DIM 11008     // out_features
#define KW_DIM 2048     // weight_q words per row (each int32 holds 1 byte = 2 nibbles)

typedef __bf16 bf16x8 __attribute__((ext_vector_type(8)));
typedef float  f32x4  __attribute__((ext_vector_type(4)));

typedef __attribute__((address_space(1))) const void gv_t;  // global
typedef __attribute__((address_space(3))) void lv_t;        // LDS

__device__ inline unsigned int bf16_rne_bits(float f) {
    unsigned int u = __float_as_uint(f);
    return (u + 0x7FFFu + ((u >> 16) & 1u)) >> 16;
}
__device__ inline unsigned int pack_bf16_pair(float lo, float hi) {
    return bf16_rne_bits(lo) | (bf16_rne_bits(hi) << 16);
}

#define NF4_INIT  {-1.0f, -0.6961928f, -0.525073f, -0.39491748f, \
                   -0.28444138f, -0.18477343f, -0.09105602f, 0.0f, \
                   0.07958029f, 0.1609302f, 0.2461123f, 0.33791524f, \
                   0.44070983f, 0.56261897f, 0.72295684f, 1.0f}

// ---------------- Pass 1a: dequantize Wq (int32 words, 1 byte each) -> bf16 ----------------
__global__ __launch_bounds__(256)
void dequant_w(const int4* __restrict__ Wq4, uint4* __restrict__ Wb4)
{
    __shared__ unsigned int lutr[256 * 32];
    const int t = threadIdx.x;
    {
        const float LUT[16] = NF4_INIT;
        const int c0 = t & 31;
        #pragma unroll
        for (int j = 0; j < 32; ++j) {
            const int e = (t >> 5) * 32 + j;
            lutr[e * 32 + c0] = pack_bf16_pair(LUT[(e >> 4) & 15], LUT[e & 15]);
        }
    }
    __syncthreads();
    const int c = t & 31;
    size_t gid = (size_t)blockIdx.x * 256 + t;
    const size_t stride = 2752u * 256u;
    #pragma unroll
    for (int it = 0; it < 8; ++it) {
        int4 w = Wq4[gid];
        uint4 o;
        o.x = lutr[(w.x & 255) * 32 + c];
        o.y = lutr[(w.y & 255) * 32 + c];
        o.z = lutr[(w.z & 255) * 32 + c];
        o.w = lutr[(w.w & 255) * 32 + c];
        Wb4[gid] = o;
        gid += stride;
    }
}

// ---------------- Pass 1b: X fp32 -> bf16 ----------------
__global__ __launch_bounds__(256)
void convert_x(const float4* __restrict__ X4, uint4* __restrict__ Xb4)
{
    size_t gid = (size_t)blockIdx.x * 256 + threadIdx.x;
    float4 a = X4[gid * 2];
    float4 b = X4[gid * 2 + 1];
    uint4 o;
    o.x = pack_bf16_pair(a.x, a.y);
    o.y = pack_bf16_pair(a.z, a.w);
    o.z = pack_bf16_pair(b.x, b.y);
    o.w = pack_bf16_pair(b.z, b.w);
    Xb4[gid] = o;
}

// ---------------- Pass 2: bf16 GEMM — 256x256 tile, BK=64, dbuf, compiler-pipelined ----------
// R2 theory: R1's per-phase {reads; barrier; lgkmcnt(0); MFMA} serialized the LDS burst and
// the MFMA burst (measured wall == LDS_time + MFMA_time). Remove the phase split and the
// explicit lgkmcnt(0); per K-tile give the compiler one straight-line block of
// 24 ds_read_b128 + 64 MFMA — hipcc emits fine-grained counted lgkmcnt (m97 asm evidence),
// letting later reads drain under earlier MFMA clusters. Counted vmcnt(8) (never 0 in loop)
// keeps the next tile's staging in flight across barriers. BK=64 halves sync events.
//
// LDS: 2 buffers x (A 32KB + B 32KB) = 128 KiB. Rows are 128 B (64 bf16).
// Swizzle (rule #21, both sides, involution): physical 16B-slot = logical slot ^ (row&7).
//   - staging: linear LDS dest (gload_lds requirement), pre-swizzled GLOBAL source col.
//   - reads:   ds_read addr col = (ks*4+quad) ^ (l16&7).
// 16 lanes/read: lanes 0-7 hit 8 distinct slots, lanes 8-15 repeat -> 2-way (free, m136).
constexpr int GBM = 256, GBN = 256, GBK = 64;
constexpr int NKT = K_DIM / GBK;             // 64
constexpr int NT2 = N_DIM / GBN;             // 43
constexpr int GRID2 = (M_DIM / GBM) * NT2;   // 688 = 8 * 86 (bijective XCD swizzle)

__global__ __launch_bounds__(512, 2)
void gemm_bk64(const unsigned short* __restrict__ Xb, const unsigned short* __restrict__ Wb,
               const float* __restrict__ scale, const float* __restrict__ bias,
               float* __restrict__ Out)
{
    __shared__ __align__(16) char lds[131072];
    char* const ldsA = lds;            // 2 buffers x 32 KB (256 rows x 128 B)
    char* const ldsB = lds + 65536;    // 2 buffers x 32 KB

    const int t = threadIdx.x;
    const int lane = t & 63;
    const int wv = t >> 6;             // 0..7
    const int wr = wv >> 2;            // 0..1 : wave owns A rows [wr*128, wr*128+128)
    const int wc = wv & 3;             // 0..3 : wave owns B rows [wc*64, wc*64+64)
    const int l16 = lane & 15, quad = lane >> 4;

    // XCD-aware bijective block swizzle (688 % 8 == 0)
    const int bid = blockIdx.x;
    const int wg = (bid & 7) * (GRID2 / 8) + (bid >> 3);
    const int m0 = (wg / NT2) * GBM;
    const int n0 = (wg % NT2) * GBN;

    // Fragment-read byte offsets (within a 32 KB buffer), swizzled per ks.
    const int r7 = l16 & 7;
    const int swz0 = ((0 + quad) ^ r7) << 4;   // ks=0: logical slot quad
    const int swz1 = ((4 + quad) ^ r7) << 4;   // ks=1: logical slot 4+quad
    const int a_rd = (wr * 128 + l16) * 128;   // + mh*8192 + i*2048 + swz
    const int b_rd = (wc * 64  + l16) * 128;   // + j*2048 + swz

    // Staging: thread t covers LDS-linear bytes [t*16, t*16+16) of each 8 KB chunk
    // (64 rows); per K-tile: 4 chunks A + 4 chunks B = 8 gloads/thread = 64 KB tile.
    // Global source column pre-swizzled with the SAME involution as the read.
    const int srow  = t >> 3;                       // 0..63 within chunk
    const int sslot = (t & 7) ^ ((t >> 3) & 7);     // physical slot t&7 holds this logical slot
    const unsigned short* sA = Xb + (size_t)(m0 + srow) * K_DIM + sslot * 8;
    const unsigned short* sB = Wb + (size_t)(n0 + srow) * K_DIM + sslot * 8;
    const int sdst = t * 16;

    f32x4 acc[8][4];
    #pragma unroll
    for (int i = 0; i < 8; ++i)
        #pragma unroll
        for (int j = 0; j < 4; ++j)
            acc[i][j] = f32x4{0.f, 0.f, 0.f, 0.f};

    // ---- prologue: stage K-tile 0 into buffer 0 (8 loads/thread) ----
    #pragma unroll
    for (int c = 0; c < 4; ++c)
        __builtin_amdgcn_global_load_lds((gv_t*)(sA + (size_t)c * 64 * K_DIM),
                                         (lv_t*)(ldsA + c * 8192 + sdst), 16, 0, 0);
    #pragma unroll
    for (int c = 0; c < 4; ++c)
        __builtin_amdgcn_global_load_lds((gv_t*)(sB + (size_t)c * 64 * K_DIM),
                                         (lv_t*)(ldsB + c * 8192 + sdst), 16, 0, 0);

    #pragma unroll 2
    for (int kt = 0; kt < NKT; ++kt) {
        const int cur = kt & 1;
        // stage K-tile kt+1 into buffer cur^1 (tail: dummy re-stage of last tile —
        // keeps vmcnt counting uniform; that buffer is never read again).
        const int kts = (kt + 1 < NKT) ? (kt + 1) : (NKT - 1);
        char* Ad = ldsA + (cur ^ 1) * 32768;
        char* Bd = ldsB + (cur ^ 1) * 32768;
        #pragma unroll
        for (int c = 0; c < 4; ++c)
            __builtin_amdgcn_global_load_lds((gv_t*)(sA + kts * 64 + (size_t)c * 64 * K_DIM),
                                             (lv_t*)(Ad + c * 8192 + sdst), 16, 0, 0);
        #pragma unroll
        for (int c = 0; c < 4; ++c)
            __builtin_amdgcn_global_load_lds((gv_t*)(sB + kts * 64 + (size_t)c * 64 * K_DIM),
                                             (lv_t*)(Bd + c * 8192 + sdst), 16, 0, 0);

        // counted wait: 8 newest outstanding = kt+1's stages -> kt fully landed.
        asm volatile("s_waitcnt vmcnt(8)" ::: "memory");
        __builtin_amdgcn_s_barrier();

        const char* Ab = ldsA + cur * 32768;
        const char* Bb = ldsB + cur * 32768;

        // ---- K-tile compute: straight-line, compiler-scheduled (no lgkmcnt(0)) ----
        {   // ks = 0
            bf16x8 af[8], bfr[4];
            #pragma unroll
            for (int i = 0; i < 4; ++i)
                af[i] = *reinterpret_cast<const bf16x8*>(Ab + a_rd + i * 2048 + swz0);
            #pragma unroll
            for (int j = 0; j < 4; ++j)
                bfr[j] = *reinterpret_cast<const bf16x8*>(Bb + b_rd + j * 2048 + swz0);
            #pragma unroll
            for (int i = 0; i < 4; ++i)
                af[4 + i] = *reinterpret_cast<const bf16x8*>(Ab + a_rd + 8192 + i * 2048 + swz0);
            __builtin_amdgcn_s_setprio(1);
            #pragma unroll
            for (int i = 0; i < 4; ++i)
                #pragma unroll
                for (int j = 0; j < 4; ++j)
                    acc[i][j] = __builtin_amdgcn_mfma_f32_16x16x32_bf16(af[i], bfr[j], acc[i][j], 0, 0, 0);
            #pragma unroll
            for (int i = 0; i < 4; ++i)
                #pragma unroll
                for (int j = 0; j < 4; ++j)
                    acc[4 + i][j] = __builtin_amdgcn_mfma_f32_16x16x32_bf16(af[4 + i], bfr[j], acc[4 + i][j], 0, 0, 0);
            __builtin_amdgcn_s_setprio(0);
        }
        {   // ks = 1
            bf16x8 af[8], bfr[4];
            #pragma unroll
            for (int i = 0; i < 4; ++i)
                af[i] = *reinterpret_cast<const bf16x8*>(Ab + a_rd + i * 2048 + swz1);
            #pragma unroll
            for (int j = 0; j < 4; ++j)
                bfr[j] = *reinterpret_cast<const bf16x8*>(Bb + b_rd + j * 2048 + swz1);
            #pragma unroll
            for (int i = 0; i < 4; ++i)
                af[4 + i] = *reinterpret_cast<const bf16x8*>(Ab + a_rd + 8192 + i * 2048 + swz1);
            __builtin_amdgcn_s_setprio(1);
            #pragma unroll
            for (int i = 0; i < 4; ++i)
                #pragma unroll
                for (int j = 0; j < 4; ++j)
                    acc[i][j] = __builtin_amdgcn_mfma_f32_16x16x32_bf16(af[i], bfr[j], acc[i][j], 0, 0, 0);
            #pragma unroll
            for (int i = 0; i < 4; ++i)
                #pragma unroll
                for (int j = 0; j < 4; ++j)
                    acc[4 + i][j] = __builtin_amdgcn_mfma_f32_16x16x32_bf16(af[4 + i], bfr[j], acc[4 + i][j], 0, 0, 0);
            __builtin_amdgcn_s_setprio(0);
        }
        // all reads of buffer `cur` consumed (MFMAs above depend on them) before anyone
        // may stage into `cur` next iteration.
        __builtin_amdgcn_s_barrier();
    }

    // drain dummy tail DMA before LDS can be handed to a successor block
    asm volatile("s_waitcnt vmcnt(0)" ::: "memory");

    // ---- epilogue: out[m][n] = acc * scale[n] + bias[n] ----
    // C/D frag: col = lane&15 (n), row = quad*4 + reg (m)
    #pragma unroll
    for (int j = 0; j < 4; ++j) {
        const int n = n0 + wc * 64 + j * 16 + l16;
        const float s  = scale[n];
        const float bz = bias[n];
        #pragma unroll
        for (int ii = 0; ii < 8; ++ii) {
            const int m = m0 + wr * 128 + ii * 16 + quad * 4;
            float* op = Out + (size_t)m * N_DIM + n;
            #pragma unroll
            for (int r = 0; r < 4; ++r)
                op[(size_t)r * N_DIM] = acc[ii][j][r] * s + bz;
        }
    }
}

// ---------------- Fallback: fused single-pass kernel (ws too small) ----------------
constexpr int BM = 128, BN = 128, BK = 64;
constexpr int F_LDK = BK + 8;
__global__ __launch_bounds__(256, 2)
void nf4_gemm_fused(const float* __restrict__ X, const int* __restrict__ Wq,
                    const float* __restrict__ scale, const float* __restrict__ bias,
                    float* __restrict__ Out)
{
    __shared__ __align__(16) unsigned short As[BM * F_LDK];
    __shared__ __align__(16) unsigned short Bs[BN * F_LDK];
    __shared__ unsigned int lut2[256];

    const int t = threadIdx.x;
    const int ntiles = N_DIM / BN;
    const int mtile = blockIdx.x / ntiles;
    const int ntile = blockIdx.x % ntiles;
    const int m0 = mtile * BM, n0 = ntile * BN;

    {
        const float LUT[16] = NF4_INIT;
        lut2[t] = pack_bf16_pair(LUT[(t >> 4) & 15], LUT[t & 15]);
    }

    const int lane = t & 63;
    const int wv = t >> 6;
    const int wr = wv >> 1, wc = wv & 1;
    const int l16 = lane & 15, quad = lane >> 4;

    const int a_r = t >> 4, a_c = (t & 15) * 4;
    const int b_r = t >> 3, b_c = (t & 7) * 4;

    const float* aptr = X + (m0 + a_r) * K_DIM + a_c;
    const int*   bptr = Wq + (n0 + b_r) * KW_DIM + b_c;

    f32x4 acc[4][4];
    #pragma unroll
    for (int i = 0; i < 4; ++i)
        #pragma unroll
        for (int j = 0; j < 4; ++j)
            acc[i][j] = f32x4{0.f, 0.f, 0.f, 0.f};

    for (int kt = 0; kt < K_DIM / BK; ++kt) {
        float4 av[8];
        int4   bv[4];
        #pragma unroll
        for (int i = 0; i < 8; ++i)
            av[i] = *reinterpret_cast<const float4*>(aptr + i * 16 * K_DIM);
        #pragma unroll
        for (int i = 0; i < 4; ++i)
            bv[i] = *reinterpret_cast<const int4*>(bptr + i * 32 * KW_DIM);
        aptr += BK;
        bptr += BK / 2;

        __syncthreads();

        #pragma unroll
        for (int i = 0; i < 8; ++i) {
            uint2 p;
            p.x = pack_bf16_pair(av[i].x, av[i].y);
            p.y = pack_bf16_pair(av[i].z, av[i].w);
            *reinterpret_cast<uint2*>(&As[(a_r + i * 16) * F_LDK + a_c]) = p;
        }
        #pragma unroll
        for (int i = 0; i < 4; ++i) {
            uint4 q;
            q.x = lut2[bv[i].x & 255];
            q.y = lut2[bv[i].y & 255];
            q.z = lut2[bv[i].z & 255];
            q.w = lut2[bv[i].w & 255];
            *reinterpret_cast<uint4*>(&Bs[(b_r + i * 32) * F_LDK + b_c * 2]) = q;
        }
        __syncthreads();

        #pragma unroll
        for (int ks = 0; ks < 2; ++ks) {
            bf16x8 af[4], bfr[4];
            const int kb = ks * 32 + quad * 8;
            #pragma unroll
            for (int i = 0; i < 4; ++i)
                af[i] = *reinterpret_cast<const bf16x8*>(&As[(wr * 64 + i * 16 + l16) * F_LDK + kb]);
            #pragma unroll
            for (int j = 0; j < 4; ++j)
                bfr[j] = *reinterpret_cast<const bf16x8*>(&Bs[(wc * 64 + j * 16 + l16) * F_LDK + kb]);
            #pragma unroll
            for (int i = 0; i < 4; ++i)
                #pragma unroll
                for (int j = 0; j < 4; ++j)
                    acc[i][j] = __builtin_amdgcn_mfma_f32_16x16x32_bf16(af[i], bfr[j], acc[i][j], 0, 0, 0);
        }
    }

    #pragma unroll
    for (int j = 0; j < 4; ++j) {
        const int n = n0 + wc * 64 + j * 16 + l16;
        const float s  = scale[n];
        const float bz = bias[n];
        #pragma unroll
        for (int i = 0; i < 4; ++i) {
            const int m = m0 + wr * 64 + i * 16 + quad * 4;
            float* op = Out + (size_t)m * N_DIM + n;
            #pragma unroll
            for (int r = 0; r < 4; ++r)
                op[(size_t)r * N_DIM] = acc[i][j][r] * s + bz;
        }
    }
}

extern "C" void kernel_launch(void* const* d_in, const int* in_sizes, int n_in,
                              void* d_out, int out_size, void* d_ws, size_t ws_size,
                              hipStream_t stream) {
    const float* X     = (const float*)d_in[0];
    const int*   Wq    = (const int*)d_in[1];
    const float* scale = (const float*)d_in[2];
    const float* bias  = (const float*)d_in[3];
    float* Out = (float*)d_out;

    const size_t WB_BYTES = (size_t)N_DIM * K_DIM * 2;   // 90,177,536
    const size_t XB_BYTES = (size_t)M_DIM * K_DIM * 2;   // 33,554,432

    if (ws_size >= WB_BYTES + XB_BYTES) {
        unsigned short* Wb = (unsigned short*)d_ws;
        unsigned short* Xb = (unsigned short*)((char*)d_ws + WB_BYTES);
        dequant_w<<<2752, 256, 0, stream>>>((const int4*)Wq, (uint4*)Wb);
        convert_x<<<8192, 256, 0, stream>>>((const float4*)X, (uint4*)Xb);
        gemm_bk64<<<GRID2, 512, 0, stream>>>(Xb, Wb, scale, bias, Out);
    } else {
        nf4_gemm_fused<<<(M_DIM / BM) * (N_DIM / BN), 256, 0, stream>>>(X, Wq, scale, bias, Out);
    }
}

// Round 3
// 609.162 us; speedup vs baseline: 1.0524x; 1.0524x over previous
//
#include <hip/hip_runtime.h>
#include <stdint.h>

// Problem constants (exact multiples of tile sizes — no bounds checks)
#define M_DIM 4096      // 2*2048 rows of x
#define K_DIM 4096      // in_features
#define N_DIM 11008     // out_features
#define KW_DIM 2048     // weight_q words per row (each int32 holds 1 byte = 2 nibbles)

typedef __bf16 bf16x8 __attribute__((ext_vector_type(8)));
typedef float  f32x4  __attribute__((ext_vector_type(4)));

typedef __attribute__((address_space(1))) const void gv_t;  // global
typedef __attribute__((address_space(3))) void lv_t;        // LDS

__device__ inline unsigned int bf16_rne_bits(float f) {
    unsigned int u = __float_as_uint(f);
    return (u + 0x7FFFu + ((u >> 16) & 1u)) >> 16;
}
__device__ inline unsigned int pack_bf16_pair(float lo, float hi) {
    return bf16_rne_bits(lo) | (bf16_rne_bits(hi) << 16);
}

#define NF4_INIT  {-1.0f, -0.6961928f, -0.525073f, -0.39491748f, \
                   -0.28444138f, -0.18477343f, -0.09105602f, 0.0f, \
                   0.07958029f, 0.1609302f, 0.2461123f, 0.33791524f, \
                   0.44070983f, 0.56261897f, 0.72295684f, 1.0f}

// ---------------- Pass 1a: dequantize Wq (int32 words, 1 byte each) -> bf16 ----------------
__global__ __launch_bounds__(256)
void dequant_w(const int4* __restrict__ Wq4, uint4* __restrict__ Wb4)
{
    __shared__ unsigned int lutr[256 * 32];
    const int t = threadIdx.x;
    {
        const float LUT[16] = NF4_INIT;
        const int c0 = t & 31;
        #pragma unroll
        for (int j = 0; j < 32; ++j) {
            const int e = (t >> 5) * 32 + j;
            lutr[e * 32 + c0] = pack_bf16_pair(LUT[(e >> 4) & 15], LUT[e & 15]);
        }
    }
    __syncthreads();
    const int c = t & 31;
    size_t gid = (size_t)blockIdx.x * 256 + t;
    const size_t stride = 2752u * 256u;
    #pragma unroll
    for (int it = 0; it < 8; ++it) {
        int4 w = Wq4[gid];
        uint4 o;
        o.x = lutr[(w.x & 255) * 32 + c];
        o.y = lutr[(w.y & 255) * 32 + c];
        o.z = lutr[(w.z & 255) * 32 + c];
        o.w = lutr[(w.w & 255) * 32 + c];
        Wb4[gid] = o;
        gid += stride;
    }
}

// ---------------- Pass 1b: X fp32 -> bf16 ----------------
__global__ __launch_bounds__(256)
void convert_x(const float4* __restrict__ X4, uint4* __restrict__ Xb4)
{
    size_t gid = (size_t)blockIdx.x * 256 + threadIdx.x;
    float4 a = X4[gid * 2];
    float4 b = X4[gid * 2 + 1];
    uint4 o;
    o.x = pack_bf16_pair(a.x, a.y);
    o.y = pack_bf16_pair(a.z, a.w);
    o.z = pack_bf16_pair(b.x, b.y);
    o.w = pack_bf16_pair(b.z, b.w);
    Xb4[gid] = o;
}

// ---------------- Pass 2: bf16 GEMM — 256x256 tile, ring-4 BK=32, pipelined reg-loads ------
// R3: attack the measured LDS/MFMA serialization (R1 wall == LDS + MFMA). Ring-4 staging
// (stage t+3 during t; vmcnt(4) at tile end => t+2 landed) makes BOTH tile t and t+1 valid
// LDS during tile t, so each phase issues the NEXT phase's ds_reads (incl. across the tile
// boundary) and waits with COUNTED lgkmcnt — reads drain under the previous MFMA burst.
// 1 barrier per tile (vs R1's 4). DS ops retire in-order per wave => counted lgkm is exact.
// Addressing/swizzle is R1-verbatim (measured: 0 bank conflicts, passed).
constexpr int GBM = 256, GBN = 256, GBK = 32;
constexpr int NKT = K_DIM / GBK;             // 128
constexpr int NT2 = N_DIM / GBN;             // 43
constexpr int GRID2 = (M_DIM / GBM) * NT2;   // 688 = 8 * 86 (bijective XCD swizzle)

__global__ __launch_bounds__(512, 2)
void gemm_r4(const unsigned short* __restrict__ Xb, const unsigned short* __restrict__ Wb,
             const float* __restrict__ scale, const float* __restrict__ bias,
             float* __restrict__ Out)
{
    __shared__ __align__(16) char lds[131072];
    char* const ldsA = lds;            // 4 buffers x 16 KB (256 rows x 64 B)
    char* const ldsB = lds + 65536;    // 4 buffers x 16 KB

    const int t = threadIdx.x;
    const int lane = t & 63;
    const int wv = t >> 6;             // 0..7
    const int wr = wv >> 2;            // 0..1 : wave owns A rows [wr*128, wr*128+128)
    const int wc = wv & 3;             // 0..3 : wave owns B rows [wc*64, wc*64+64)
    const int l16 = lane & 15, quad = lane >> 4;

    // XCD-aware bijective block swizzle (688 % 8 == 0)
    const int bid = blockIdx.x;
    const int wg = (bid & 7) * (GRID2 / 8) + (bid >> 3);
    const int m0 = (wg / NT2) * GBM;
    const int n0 = (wg % NT2) * GBN;

    // Fragment-read byte offsets within a 16 KB buffer (R1-verbatim, 0 conflicts measured).
    const int swz = ((quad ^ ((l16 >> 1) & 3)) << 4);
    const int a_rd = (wr * 128 + l16) * 64 + swz;   // + i*1024 (i*16 rows); +4096 for rows 64-127
    const int b_rd = (wc * 64  + l16) * 64 + swz;   // + j*1024

    // Staging (R1-verbatim): thread t covers LDS-linear bytes [t*16, t*16+16) of an 8 KB
    // chunk (row = t>>2, slot = t&3); global source column pre-swizzled (same involution).
    const int srow  = t >> 2;                       // 0..127
    const int sslot = (t & 3) ^ ((t >> 3) & 3);
    const unsigned short* sA = Xb + (size_t)(m0 + srow) * K_DIM + sslot * 8;
    const unsigned short* sB = Wb + (size_t)(n0 + srow) * K_DIM + sslot * 8;
    const int sdst = t * 16;

    f32x4 acc[8][4];
    #pragma unroll
    for (int i = 0; i < 8; ++i)
        #pragma unroll
        for (int j = 0; j < 4; ++j)
            acc[i][j] = f32x4{0.f, 0.f, 0.f, 0.f};

    bf16x8 a0[2][4], bfrag[2][4], a1[4];

    // ---- prologue: stage tiles 0,1,2 into buffers 0,1,2 (12 gloads) ----
    #pragma unroll
    for (int c = 0; c < 3; ++c) {
        char* Ad = ldsA + c * 16384;
        char* Bd = ldsB + c * 16384;
        __builtin_amdgcn_global_load_lds((gv_t*)(sA + c * 32),
                                         (lv_t*)(Ad + sdst), 16, 0, 0);
        __builtin_amdgcn_global_load_lds((gv_t*)(sA + c * 32 + (size_t)128 * K_DIM),
                                         (lv_t*)(Ad + 8192 + sdst), 16, 0, 0);
        __builtin_amdgcn_global_load_lds((gv_t*)(sB + c * 32),
                                         (lv_t*)(Bd + sdst), 16, 0, 0);
        __builtin_amdgcn_global_load_lds((gv_t*)(sB + c * 32 + (size_t)128 * K_DIM),
                                         (lv_t*)(Bd + 8192 + sdst), 16, 0, 0);
    }
    asm volatile("s_waitcnt vmcnt(4)" ::: "memory");   // tiles 0,1 fully landed
    __builtin_amdgcn_s_barrier();

    // preload P0(0) fragments (stay outstanding: lgkm=8 entering tile 0)
    #pragma unroll
    for (int i = 0; i < 4; ++i)
        a0[0][i] = *reinterpret_cast<const bf16x8*>(ldsA + a_rd + i * 1024);
    #pragma unroll
    for (int j = 0; j < 4; ++j)
        bfrag[0][j] = *reinterpret_cast<const bf16x8*>(ldsB + b_rd + j * 1024);

// One tile: 2 phases, 1 barrier. PH = kt&3 (compile-time), reg parity = PH&1.
#define TILE(KT, PH)                                                                 \
  {                                                                                  \
    const char* Abuf = ldsA + (PH) * 16384;                                          \
    char* AdS = ldsA + (((PH) + 3) & 3) * 16384;                                     \
    char* BdS = ldsB + (((PH) + 3) & 3) * 16384;                                     \
    const char* Anx = ldsA + (((PH) + 1) & 3) * 16384;                               \
    const char* Bnx = ldsB + (((PH) + 1) & 3) * 16384;                               \
    const int kts = ((KT) + 3 < NKT) ? ((KT) + 3) : (NKT - 1);                       \
    /* P0: stage A(t+3); issue A1(t); wait a0/b(t); MFMA rows 0-63 */                \
    __builtin_amdgcn_global_load_lds((gv_t*)(sA + kts * 32),                         \
                                     (lv_t*)(AdS + sdst), 16, 0, 0);                 \
    __builtin_amdgcn_global_load_lds((gv_t*)(sA + kts * 32 + (size_t)128 * K_DIM),   \
                                     (lv_t*)(AdS + 8192 + sdst), 16, 0, 0);          \
    _Pragma("unroll")                                                                \
    for (int i = 0; i < 4; ++i)                                                      \
      a1[i] = *reinterpret_cast<const bf16x8*>(Abuf + a_rd + 4096 + i * 1024);       \
    asm volatile("s_waitcnt lgkmcnt(4)" ::: "memory");                               \
    __builtin_amdgcn_sched_barrier(0);                                               \
    __builtin_amdgcn_s_setprio(1);                                                   \
    _Pragma("unroll")                                                                \
    for (int i = 0; i < 4; ++i)                                                      \
      _Pragma("unroll")                                                              \
      for (int j = 0; j < 4; ++j)                                                    \
        acc[i][j] = __builtin_amdgcn_mfma_f32_16x16x32_bf16(a0[(PH) & 1][i],         \
                        bfrag[(PH) & 1][j], acc[i][j], 0, 0, 0);                     \
    __builtin_amdgcn_s_setprio(0);                                                   \
    /* P1: stage B(t+3); issue a0/b(t+1); wait A1(t); MFMA rows 64-127 */            \
    __builtin_amdgcn_global_load_lds((gv_t*)(sB + kts * 32),                         \
                                     (lv_t*)(BdS + sdst), 16, 0, 0);                 \
    __builtin_amdgcn_global_load_lds((gv_t*)(sB + kts * 32 + (size_t)128 * K_DIM),   \
                                     (lv_t*)(BdS + 8192 + sdst), 16, 0, 0);          \
    _Pragma("unroll")                                                                \
    for (int i = 0; i < 4; ++i)                                                      \
      a0[((PH) + 1) & 1][i] = *reinterpret_cast<const bf16x8*>(Anx + a_rd + i * 1024); \
    _Pragma("unroll")                                                                \
    for (int j = 0; j < 4; ++j)                                                      \
      bfrag[((PH) + 1) & 1][j] = *reinterpret_cast<const bf16x8*>(Bnx + b_rd + j * 1024); \
    asm volatile("s_waitcnt lgkmcnt(8)" ::: "memory");                               \
    __builtin_amdgcn_sched_barrier(0);                                               \
    __builtin_amdgcn_s_setprio(1);                                                   \
    _Pragma("unroll")                                                                \
    for (int i = 0; i < 4; ++i)                                                      \
      _Pragma("unroll")                                                              \
      for (int j = 0; j < 4; ++j)                                                    \
        acc[4 + i][j] = __builtin_amdgcn_mfma_f32_16x16x32_bf16(a1[i],               \
                        bfrag[(PH) & 1][j], acc[4 + i][j], 0, 0, 0);                 \
    __builtin_amdgcn_s_setprio(0);                                                   \
    asm volatile("s_waitcnt vmcnt(4)" ::: "memory");                                 \
    __builtin_amdgcn_s_barrier();                                                    \
  }

    for (int kt4 = 0; kt4 < NKT; kt4 += 4) {
        TILE(kt4 + 0, 0)
        TILE(kt4 + 1, 1)
        TILE(kt4 + 2, 2)
        TILE(kt4 + 3, 3)
    }
#undef TILE

    // keep the tail pipeline reads live (rule #17): if DCE'd, the last tile's counted
    // lgkmcnt(8) would under-wait and consume A1 before it lands.
    #pragma unroll
    for (int i = 0; i < 4; ++i)
        asm volatile("" :: "v"(a0[0][i]), "v"(bfrag[0][i]), "v"(a1[i]));

    // drain dummy tail staging before LDS can be handed to a successor block
    asm volatile("s_waitcnt vmcnt(0)" ::: "memory");

    // ---- epilogue: out[m][n] = acc * scale[n] + bias[n] ----
    // C/D frag: col = lane&15 (n), row = quad*4 + reg (m)
    #pragma unroll
    for (int j = 0; j < 4; ++j) {
        const int n = n0 + wc * 64 + j * 16 + l16;
        const float s  = scale[n];
        const float bz = bias[n];
        #pragma unroll
        for (int ii = 0; ii < 8; ++ii) {
            const int m = m0 + wr * 128 + ii * 16 + quad * 4;
            float* op = Out + (size_t)m * N_DIM + n;
            #pragma unroll
            for (int r = 0; r < 4; ++r)
                op[(size_t)r * N_DIM] = acc[ii][j][r] * s + bz;
        }
    }
}

// ---------------- Fallback: fused single-pass kernel (ws too small) ----------------
constexpr int BM = 128, BN = 128, BK = 64;
constexpr int F_LDK = BK + 8;
__global__ __launch_bounds__(256, 2)
void nf4_gemm_fused(const float* __restrict__ X, const int* __restrict__ Wq,
                    const float* __restrict__ scale, const float* __restrict__ bias,
                    float* __restrict__ Out)
{
    __shared__ __align__(16) unsigned short As[BM * F_LDK];
    __shared__ __align__(16) unsigned short Bs[BN * F_LDK];
    __shared__ unsigned int lut2[256];

    const int t = threadIdx.x;
    const int ntiles = N_DIM / BN;
    const int mtile = blockIdx.x / ntiles;
    const int ntile = blockIdx.x % ntiles;
    const int m0 = mtile * BM, n0 = ntile * BN;

    {
        const float LUT[16] = NF4_INIT;
        lut2[t] = pack_bf16_pair(LUT[(t >> 4) & 15], LUT[t & 15]);
    }

    const int lane = t & 63;
    const int wv = t >> 6;
    const int wr = wv >> 1, wc = wv & 1;
    const int l16 = lane & 15, quad = lane >> 4;

    const int a_r = t >> 4, a_c = (t & 15) * 4;
    const int b_r = t >> 3, b_c = (t & 7) * 4;

    const float* aptr = X + (m0 + a_r) * K_DIM + a_c;
    const int*   bptr = Wq + (n0 + b_r) * KW_DIM + b_c;

    f32x4 acc[4][4];
    #pragma unroll
    for (int i = 0; i < 4; ++i)
        #pragma unroll
        for (int j = 0; j < 4; ++j)
            acc[i][j] = f32x4{0.f, 0.f, 0.f, 0.f};

    for (int kt = 0; kt < K_DIM / BK; ++kt) {
        float4 av[8];
        int4   bv[4];
        #pragma unroll
        for (int i = 0; i < 8; ++i)
            av[i] = *reinterpret_cast<const float4*>(aptr + i * 16 * K_DIM);
        #pragma unroll
        for (int i = 0; i < 4; ++i)
            bv[i] = *reinterpret_cast<const int4*>(bptr + i * 32 * KW_DIM);
        aptr += BK;
        bptr += BK / 2;

        __syncthreads();

        #pragma unroll
        for (int i = 0; i < 8; ++i) {
            uint2 p;
            p.x = pack_bf16_pair(av[i].x, av[i].y);
            p.y = pack_bf16_pair(av[i].z, av[i].w);
            *reinterpret_cast<uint2*>(&As[(a_r + i * 16) * F_LDK + a_c]) = p;
        }
        #pragma unroll
        for (int i = 0; i < 4; ++i) {
            uint4 q;
            q.x = lut2[bv[i].x & 255];
            q.y = lut2[bv[i].y & 255];
            q.z = lut2[bv[i].z & 255];
            q.w = lut2[bv[i].w & 255];
            *reinterpret_cast<uint4*>(&Bs[(b_r + i * 32) * F_LDK + b_c * 2]) = q;
        }
        __syncthreads();

        #pragma unroll
        for (int ks = 0; ks < 2; ++ks) {
            bf16x8 af[4], bfr[4];
            const int kb = ks * 32 + quad * 8;
            #pragma unroll
            for (int i = 0; i < 4; ++i)
                af[i] = *reinterpret_cast<const bf16x8*>(&As[(wr * 64 + i * 16 + l16) * F_LDK + kb]);
            #pragma unroll
            for (int j = 0; j < 4; ++j)
                bfr[j] = *reinterpret_cast<const bf16x8*>(&Bs[(wc * 64 + j * 16 + l16) * F_LDK + kb]);
            #pragma unroll
            for (int i = 0; i < 4; ++i)
                #pragma unroll
                for (int j = 0; j < 4; ++j)
                    acc[i][j] = __builtin_amdgcn_mfma_f32_16x16x32_bf16(af[i], bfr[j], acc[i][j], 0, 0, 0);
        }
    }

    #pragma unroll
    for (int j = 0; j < 4; ++j) {
        const int n = n0 + wc * 64 + j * 16 + l16;
        const float s  = scale[n];
        const float bz = bias[n];
        #pragma unroll
        for (int i = 0; i < 4; ++i) {
            const int m = m0 + wr * 64 + i * 16 + quad * 4;
            float* op = Out + (size_t)m * N_DIM + n;
            #pragma unroll
            for (int r = 0; r < 4; ++r)
                op[(size_t)r * N_DIM] = acc[i][j][r] * s + bz;
        }
    }
}

extern "C" void kernel_launch(void* const* d_in, const int* in_sizes, int n_in,
                              void* d_out, int out_size, void* d_ws, size_t ws_size,
                              hipStream_t stream) {
    const float* X     = (const float*)d_in[0];
    const int*   Wq    = (const int*)d_in[1];
    const float* scale = (const float*)d_in[2];
    const float* bias  = (const float*)d_in[3];
    float* Out = (float*)d_out;

    const size_t WB_BYTES = (size_t)N_DIM * K_DIM * 2;   // 90,177,536
    const size_t XB_BYTES = (size_t)M_DIM * K_DIM * 2;   // 33,554,432

    if (ws_size >= WB_BYTES + XB_BYTES) {
        unsigned short* Wb = (unsigned short*)d_ws;
        unsigned short* Xb = (unsigned short*)((char*)d_ws + WB_BYTES);
        dequant_w<<<2752, 256, 0, stream>>>((const int4*)Wq, (uint4*)Wb);
        convert_x<<<8192, 256, 0, stream>>>((const float4*)X, (uint4*)Xb);
        gemm_r4<<<GRID2, 512, 0, stream>>>(Xb, Wb, scale, bias, Out);
    } else {
        nf4_gemm_fused<<<(M_DIM / BM) * (N_DIM / BN), 256, 0, stream>>>(X, Wq, scale, bias, Out);
    }
}